// Round 7
// baseline (43047.430 us; speedup 1.0000x reference)
//
#include <hip/hip_runtime.h>

#define TSTEPS 1920
#define NB 128
#define HIDN 256
#define LATN 128
#define EPSF 1e-5f

typedef __attribute__((ext_vector_type(8))) short bf16x8;
typedef __attribute__((ext_vector_type(4))) float f32x4;

__device__ __forceinline__ unsigned short f2bf(float x) {
    unsigned u = __builtin_bit_cast(unsigned, x);
    unsigned r = (u + 0x7fffu + ((u >> 16) & 1u)) >> 16;
    return (unsigned short)r;
}
__device__ __forceinline__ float bf2f(unsigned short h) {
    unsigned u = ((unsigned)h) << 16;
    return __builtin_bit_cast(float, u);
}
__device__ __forceinline__ float u32lo(unsigned w) {
    return __builtin_bit_cast(float, w << 16);
}
__device__ __forceinline__ float u32hi(unsigned w) {
    return __builtin_bit_cast(float, w & 0xFFFF0000u);
}
__device__ __forceinline__ float fsig(float x) {
    float e = __expf(-fabsf(x));
    float s = 1.f / (1.f + e);
    return x >= 0.f ? s : 1.f - s;
}
__device__ __forceinline__ float ftanh(float x) {
    float e = __expf(-2.f * fabsf(x));
    float r = (1.f - e) / (1.f + e);
    return x >= 0.f ? r : -r;
}
__device__ __forceinline__ float fleaky(float x) { return x > 0.f ? x : 0.2f * x; }
__device__ __forceinline__ bf16x8 bcast16(uint4 v) { return __builtin_bit_cast(bf16x8, v); }

__device__ __forceinline__ unsigned aload(const unsigned* p) {
    return __hip_atomic_load(p, __ATOMIC_RELAXED, __HIP_MEMORY_SCOPE_AGENT);
}
__device__ __forceinline__ unsigned long long aload64(const unsigned long long* p) {
    return __hip_atomic_load(p, __ATOMIC_RELAXED, __HIP_MEMORY_SCOPE_AGENT);
}
__device__ __forceinline__ void astore(unsigned* p, unsigned v) {
    __hip_atomic_store(p, v, __ATOMIC_RELAXED, __HIP_MEMORY_SCOPE_AGENT);
}

#define MFMA(a, b, c) __builtin_amdgcn_mfma_f32_16x16x32_bf16((a), (b), (c), 0, 0, 0)

#define FLG(ph, g, s) (((ph) * 8 + (g)) * 8 + (s)) * 32
#define HPLANE(g, layer, buf) (((g) * 2 + (layer)) * 2 + (buf)) * 4096

__global__ void init_sync(unsigned* hbuf, unsigned* flags) {
    int i = blockIdx.x * 256 + threadIdx.x;
    if (i < 131072) hbuf[i] = 0u;
    if (i < 4096) flags[i] = 0u;
}

__global__ void pack_bfrag_sliced(const float* __restrict__ A, const float* __restrict__ Bsrc,
                                  int KA, int KB,
                                  unsigned short* __restrict__ hi, unsigned short* __restrict__ lo) {
    int e = blockIdx.x * 256 + threadIdx.x;
    int K = KA + KB;
    int KT = K >> 5;
    if (e >= 1024 * K) return;
    int j = e & 7;
    int l = (e >> 3) & 63;
    int r = e >> 9;
    int kt = r % KT;
    int r2 = r / KT;
    int v = r2 & 7;
    int w = r2 >> 3;
    int n = (v >> 1) * 256 + 32 * w + 16 * (v & 1) + (l & 15);
    int k = kt * 32 + (l >> 4) * 8 + j;
    float val = (k < KA) ? A[n * KA + k] : Bsrc[n * KB + (k - KA)];
    unsigned short h = f2bf(val);
    hi[e] = h;
    lo[e] = f2bf(val - bf2f(h));
}

__global__ void pack_sw1k8(const float* __restrict__ sW1, unsigned short* __restrict__ out) {
    int e = blockIdx.x * 256 + threadIdx.x;
    if (e >= 256 * 128) return;
    int j = e & 127, k = e >> 7;
    out[((k >> 3) * 128 + j) * 8 + (k & 7)] = f2bf(sW1[j * 256 + k]);
}

__global__ void pack4T(const float* __restrict__ W, int N, int K, float* __restrict__ out) {
    int e = blockIdx.x * 256 + threadIdx.x;
    if (e >= N * K) return;
    int j = e & 3;
    int rest = e >> 2;
    int n = rest % N;
    int k4 = rest / N;
    out[e] = W[n * K + 4 * k4 + j];
}

__global__ void prep_b1(const float* __restrict__ bih1, const float* __restrict__ bhh1,
                        float* __restrict__ b1sum) {
    int i = blockIdx.x * 256 + threadIdx.x;
    if (i < 1024) b1sum[i] = bih1[i] + bhh1[i];
}

__global__ void np_head(const float* __restrict__ z, const int* __restrict__ labels,
                        const float* __restrict__ emb_W, const float* __restrict__ np_W,
                        const float* __restrict__ np_b, const float* __restrict__ np_g,
                        const float* __restrict__ np_be, float* __restrict__ x_const) {
    int b = blockIdx.x;
    int j = threadIdx.x;
    __shared__ float xc[LATN + HIDN];
    __shared__ float red[8];
    int lab = labels[b];
    if (j < LATN) xc[j] = z[b * LATN + j];
    float e = emb_W[lab * HIDN + j];
    xc[LATN + j] = e;
    __syncthreads();
    float d = np_b[j];
    for (int k = 0; k < LATN + HIDN; ++k) d += xc[k] * np_W[j * (LATN + HIDN) + k];
    int lane = j & 63, wv = j >> 6;
    float s = d, s2 = d * d;
    for (int o = 1; o < 64; o <<= 1) { s += __shfl_xor(s, o); s2 += __shfl_xor(s2, o); }
    if (lane == 0) { red[wv] = s; red[4 + wv] = s2; }
    __syncthreads();
    float S = red[0] + red[1] + red[2] + red[3];
    float S2 = red[4] + red[5] + red[6] + red[7];
    float m = S * (1.f / 256.f);
    float var = S2 * (1.f / 256.f) - m * m;
    float h = fleaky((d - m) * rsqrtf(var + EPSF) * np_g[j] + np_be[j]);
    x_const[b * 512 + j] = h;
    x_const[b * 512 + 256 + j] = e;
}

__global__ void __launch_bounds__(1024) xw0_kernel(const float* __restrict__ x_const,
                                                   const float4* __restrict__ Wih0T4,
                                                   const float* __restrict__ bih0,
                                                   const float* __restrict__ bhh0,
                                                   float* __restrict__ xw0) {
    int b = blockIdx.x;
    int g = threadIdx.x;
    __shared__ float xc[512];
    if (g < 512) xc[g] = x_const[b * 512 + g];
    __syncthreads();
    const float4* xc4 = (const float4*)xc;
    float4 acc = {0.f, 0.f, 0.f, 0.f};
#pragma unroll 8
    for (int k4 = 0; k4 < 128; ++k4) {
        float4 w = Wih0T4[k4 * 1024 + g];
        float4 x = xc4[k4];
        acc.x = fmaf(w.x, x.x, acc.x);
        acc.y = fmaf(w.y, x.y, acc.y);
        acc.z = fmaf(w.z, x.z, acc.z);
        acc.w = fmaf(w.w, x.w, acc.w);
    }
    xw0[b * 1024 + g] = bih0[g] + bhh0[g] + ((acc.x + acc.y) + (acc.z + acc.w));
}

// ==== main recurrent kernel: 32 blocks (4 pairs x 8 slices) x 512 thr, 2 groups/block ====
__global__ void __launch_bounds__(512, 2) lstm_coop(
    const uint4* __restrict__ whh0h, const uint4* __restrict__ whh0l,
    const uint4* __restrict__ w1h, const uint4* __restrict__ w1l,
    const unsigned short* __restrict__ sw1k8_g, const float* __restrict__ xw0g,
    const float* __restrict__ b1sum, const float* __restrict__ sb1,
    const float* __restrict__ sg, const float* __restrict__ sbe,
    const float* __restrict__ sW2, const float* __restrict__ sb2,
    unsigned* __restrict__ hbuf, unsigned* __restrict__ flags,
    float* __restrict__ base_out, float* __restrict__ hsum_out) {
    extern __shared__ char smem[];
    char* pAhi = smem;                     // [16][512] u16 (h0 @0, h1 @512B) group A
    char* pAlo = smem + 16384;
    char* pBhi = smem + 32768;
    char* pBlo = smem + 49152;
    unsigned short* sw1s = (unsigned short*)(smem + 65536);  // 64KB
    float* gatesLA = (float*)(smem + 131072);                // [16][132]
    float* gatesLB = (float*)(smem + 139520);
    float* ppartA = (float*)(smem + 147968);                 // [2][4][128]
    float* ppartB = (float*)(smem + 152064);                 // ends 156160

    const int W = blockIdx.x & 7;          // slice
    const int q = blockIdx.x >> 3;         // pair 0..3
    const int gA = 2 * q, gB = 2 * q + 1;
    const int tid = threadIdx.x;
    const int l = tid & 63;
    const int v = tid >> 6;                // wave 0..7
    const int ln16 = l & 15;
    const int kg = l >> 4;

    for (int i = tid; i < 256 * 128; i += 512) sw1s[i] = sw1k8_g[i];
    for (int i = tid; i < 4096; i += 512) {
        ((unsigned*)pAhi)[i] = 0u; ((unsigned*)pAlo)[i] = 0u;
        ((unsigned*)pBhi)[i] = 0u; ((unsigned*)pBlo)[i] = 0u;
    }

    // resident weights: Whh0 hi+lo (64 regs) + W1 hi (64 regs)
    uint4 b0h[8], b0l[8];
#pragma unroll
    for (int kt = 0; kt < 8; ++kt) {
        int idx = ((W * 8 + v) * 8 + kt) * 64 + l;
        b0h[kt] = whh0h[idx];
        b0l[kt] = whh0l[idx];
    }
    uint4 w1hR[16];
#pragma unroll
    for (int kt = 0; kt < 16; ++kt) w1hR[kt] = w1h[((W * 8 + v) * 16 + kt) * 64 + l];
    const uint4* w1lb = w1l + ((W * 8 + v) * 16) * 64 + l;

    const int row = tid >> 5;              // batch row 0..15
    const int ul = tid & 31;
    const int ug = 32 * W + ul;            // unit 0..255
    float xwiA[4], xwiB[4], b1v[4];
#pragma unroll
    for (int gt = 0; gt < 4; ++gt) {
        xwiA[gt] = xw0g[(gA * 16 + row) * 1024 + gt * 256 + ug];
        xwiB[gt] = xw0g[(gB * 16 + row) * 1024 + gt * 256 + ug];
        b1v[gt] = b1sum[gt * 256 + ug];
    }
    float c0A = 0.f, c0B = 0.f, c1A = 0.f, c1B = 0.f, hsA = 0.f, hsB = 0.f;

    const float sb1a = sb1[l], sb1b = sb1[64 + l];
    const float sga = sg[l], sgb = sg[64 + l];
    const float sbea = sbe[l], sbeb = sbe[64 + l];
    const float sw2a = sW2[l], sw2b = sW2[64 + l];
    const float sb2v = sb2[0];

    unsigned* h0A[2] = {hbuf + HPLANE(gA, 0, 0), hbuf + HPLANE(gA, 0, 1)};
    unsigned* h1A[2] = {hbuf + HPLANE(gA, 1, 0), hbuf + HPLANE(gA, 1, 1)};
    unsigned* h0B[2] = {hbuf + HPLANE(gB, 0, 0), hbuf + HPLANE(gB, 0, 1)};
    unsigned* h1B[2] = {hbuf + HPLANE(gB, 1, 0), hbuf + HPLANE(gB, 1, 1)};
    unsigned* fl0 = flags + FLG(0, q, W);
    unsigned* fl1 = flags + FLG(1, q, W);
    unsigned* fl0base = flags + FLG(0, q, 0);
    unsigned* fl1base = flags + FLG(1, q, 0);

    const int abase = ln16 * 1024;
    const int aswz = (ln16 & 7) << 4;
    const int kgo = kg * 16;
    const int gcol = (v >> 1) * 32 + (v & 1) * 16 + ln16;
    const int hprow = 2 * W + (v & 1);
    const int hpswz = (hprow & 7) << 4;
    const int kq = v >> 1;
    const int rpar = v & 1;

#define STAGE(srcA, srcB, baseByte)                                              \
    {                                                                            \
        _Pragma("unroll")                                                        \
        for (int it = 0; it < 4; ++it) {                                         \
            int i2 = tid + 512 * it;                                             \
            int r_ = i2 >> 7, u2 = i2 & 127;                                     \
            int off = r_ * 1024 + (((baseByte) + 4 * u2) ^ ((r_ & 7) << 4));     \
            unsigned long long vA = aload64(                                     \
                (const unsigned long long*)(srcA) + r_ * 128 + u2);              \
            unsigned a0 = (unsigned)vA, a1 = (unsigned)(vA >> 32);               \
            *(unsigned*)(pAhi + off) = (a0 >> 16) | (a1 & 0xffff0000u);          \
            *(unsigned*)(pAlo + off) = (a0 & 0xffffu) | (a1 << 16);              \
            unsigned long long vB = aload64(                                     \
                (const unsigned long long*)(srcB) + r_ * 128 + u2);              \
            unsigned e0 = (unsigned)vB, e1 = (unsigned)(vB >> 32);               \
            *(unsigned*)(pBhi + off) = (e0 >> 16) | (e1 & 0xffff0000u);          \
            *(unsigned*)(pBlo + off) = (e0 & 0xffffu) | (e1 << 16);              \
        }                                                                        \
    }

#define HEADPART                                                                 \
    {                                                                            \
        float pAa = 0.f, pAb = 0.f, pBa = 0.f, pBb = 0.f;                        \
        int hb = hprow * 1024;                                                   \
        _Pragma("unroll")                                                        \
        for (int kc = 0; kc < 8; ++kc) {                                         \
            int kb = kq * 64 + kc * 8;                                           \
            int poff = hb + ((512 + 2 * kb) ^ hpswz);                            \
            uint4 hiA = *(const uint4*)(pAhi + poff);                            \
            uint4 loA = *(const uint4*)(pAlo + poff);                            \
            uint4 hiB = *(const uint4*)(pBhi + poff);                            \
            uint4 loB = *(const uint4*)(pBlo + poff);                            \
            int idx8 = kq * 8 + kc;                                              \
            uint4 wa4 = *(const uint4*)&sw1s[(idx8 * 128 + l) * 8];              \
            uint4 wb4 = *(const uint4*)&sw1s[(idx8 * 128 + 64 + l) * 8];         \
            _Pragma("unroll")                                                    \
            for (int q_ = 0; q_ < 4; ++q_) {                                     \
                unsigned hwA = ((const unsigned*)&hiA)[q_];                      \
                unsigned lwA = ((const unsigned*)&loA)[q_];                      \
                float heA = u32lo(hwA) + u32lo(lwA);                             \
                float hoA = u32hi(hwA) + u32hi(lwA);                             \
                unsigned hwB = ((const unsigned*)&hiB)[q_];                      \
                unsigned lwB = ((const unsigned*)&loB)[q_];                      \
                float heB = u32lo(hwB) + u32lo(lwB);                             \
                float hoB = u32hi(hwB) + u32hi(lwB);                             \
                unsigned wa = ((const unsigned*)&wa4)[q_];                       \
                unsigned wb = ((const unsigned*)&wb4)[q_];                       \
                pAa = fmaf(u32lo(wa), heA, pAa); pAa = fmaf(u32hi(wa), hoA, pAa);\
                pAb = fmaf(u32lo(wb), heA, pAb); pAb = fmaf(u32hi(wb), hoA, pAb);\
                pBa = fmaf(u32lo(wa), heB, pBa); pBa = fmaf(u32hi(wa), hoB, pBa);\
                pBb = fmaf(u32lo(wb), heB, pBb); pBb = fmaf(u32hi(wb), hoB, pBb);\
            }                                                                    \
        }                                                                        \
        ppartA[rpar * 512 + kq * 128 + l] = pAa;                                 \
        ppartA[rpar * 512 + kq * 128 + 64 + l] = pAb;                            \
        ppartB[rpar * 512 + kq * 128 + l] = pBa;                                 \
        ppartB[rpar * 512 + kq * 128 + 64 + l] = pBb;                            \
    }

#define HEADFIN(tout)                                                            \
    if (v < 4) {                                                                 \
        const float* pp = (v >> 1) ? ppartB : ppartA;                            \
        int rp = v & 1;                                                          \
        float sA = sb1a, sB = sb1b;                                              \
        _Pragma("unroll")                                                        \
        for (int q_ = 0; q_ < 4; ++q_) {                                         \
            sA += pp[rp * 512 + q_ * 128 + l];                                   \
            sB += pp[rp * 512 + q_ * 128 + 64 + l];                              \
        }                                                                        \
        float ssum = sA + sB, ssq = sA * sA + sB * sB;                           \
        _Pragma("unroll")                                                        \
        for (int o = 1; o < 64; o <<= 1) {                                       \
            ssum += __shfl_xor(ssum, o); ssq += __shfl_xor(ssq, o);              \
        }                                                                        \
        float m = ssum * (1.f / 128.f);                                          \
        float var = ssq * (1.f / 128.f) - m * m;                                 \
        float rstd = rsqrtf(var + EPSF);                                         \
        float p0 = fleaky((sA - m) * rstd * sga + sbea);                         \
        float p1 = fleaky((sB - m) * rstd * sgb + sbeb);                         \
        float qd = p0 * sw2a + p1 * sw2b;                                        \
        _Pragma("unroll")                                                        \
        for (int o = 1; o < 64; o <<= 1) qd += __shfl_xor(qd, o);                \
        int grow = ((v >> 1) ? gB : gA) * 16 + 2 * W + rp;                       \
        if (l == 0) base_out[grow * TSTEPS + (tout)] = ftanh(qd + sb2v);         \
    }

#define WAITF(basep, tgtv)                                                       \
    {                                                                            \
        unsigned tgt = (unsigned)(tgtv);                                         \
        while (true) {                                                           \
            unsigned val = (l < 8) ? aload((basep) + l * 32) : tgt;              \
            if (__all((int)(val >= tgt))) break;                                 \
            __builtin_amdgcn_s_sleep(1);                                         \
        }                                                                        \
    }                                                                            \
    asm volatile("" ::: "memory");

    __syncthreads();

    for (int t = 0; t < TSTEPS; ++t) {
        const int cur = t & 1, prev = cur ^ 1;
        // ---- stage h1(t-1) both groups ----
        WAITF(fl1base, t);
        STAGE(h1A[prev], h1B[prev], 512);
        __syncthreads();  // bar0
        // ---- prefetch w1l kt 8..15 ----
        uint4 lb[8];
#pragma unroll
        for (int kt = 0; kt < 8; ++kt) lb[kt] = w1lb[(8 + kt) * 64];
        // ---- MV0 both groups ----
        {
            f32x4 aA = {0.f, 0.f, 0.f, 0.f}, aB = {0.f, 0.f, 0.f, 0.f};
#pragma unroll
            for (int kt = 0; kt < 8; ++kt) {
                int aoff = abase + ((kt * 64 + kgo) ^ aswz);
                bf16x8 ahiA = bcast16(*(const uint4*)(pAhi + aoff));
                bf16x8 aloA = bcast16(*(const uint4*)(pAlo + aoff));
                bf16x8 ahiB = bcast16(*(const uint4*)(pBhi + aoff));
                bf16x8 aloB = bcast16(*(const uint4*)(pBlo + aoff));
                bf16x8 bh = bcast16(b0h[kt]);
                bf16x8 bl = bcast16(b0l[kt]);
                aA = MFMA(ahiA, bh, aA); aA = MFMA(aloA, bh, aA); aA = MFMA(ahiA, bl, aA);
                aB = MFMA(ahiB, bh, aB); aB = MFMA(aloB, bh, aB); aB = MFMA(ahiB, bl, aB);
            }
#pragma unroll
            for (int r = 0; r < 4; ++r) {
                gatesLA[(kg * 4 + r) * 132 + gcol] = aA[r];
                gatesLB[(kg * 4 + r) * 132 + gcol] = aB[r];
            }
        }
        // ---- MV1 partB (Whh1 @ h1(t-1)) both groups ----
        f32x4 acc1A = {0.f, 0.f, 0.f, 0.f}, acc1B = {0.f, 0.f, 0.f, 0.f};
#pragma unroll
        for (int kt = 8; kt < 16; ++kt) {
            int aoff = abase + ((kt * 64 + kgo) ^ aswz);
            bf16x8 ahiA = bcast16(*(const uint4*)(pAhi + aoff));
            bf16x8 aloA = bcast16(*(const uint4*)(pAlo + aoff));
            bf16x8 ahiB = bcast16(*(const uint4*)(pBhi + aoff));
            bf16x8 aloB = bcast16(*(const uint4*)(pBlo + aoff));
            bf16x8 bh = bcast16(w1hR[kt]);
            bf16x8 bl = bcast16(lb[kt - 8]);
            acc1A = MFMA(ahiA, bh, acc1A); acc1A = MFMA(aloA, bh, acc1A); acc1A = MFMA(ahiA, bl, acc1A);
            acc1B = MFMA(ahiB, bh, acc1B); acc1B = MFMA(aloB, bh, acc1B); acc1B = MFMA(ahiB, bl, acc1B);
        }
        // ---- head partials (h1(t-1)), shared sW1 loads ----
        HEADPART;
        __syncthreads();  // bar1
        // ---- UPD0 both groups -> publish h0(t) ----
        {
            float i_ = gatesLA[row * 132 + ul] + xwiA[0];
            float f_ = gatesLA[row * 132 + 32 + ul] + xwiA[1];
            float g_ = gatesLA[row * 132 + 64 + ul] + xwiA[2];
            float o_ = gatesLA[row * 132 + 96 + ul] + xwiA[3];
            c0A = fsig(f_) * c0A + fsig(i_) * ftanh(g_);
            float h = fsig(o_) * ftanh(c0A);
            unsigned short hh = f2bf(h);
            unsigned short ll = f2bf(h - bf2f(hh));
            astore(h0A[cur] + row * 256 + ug, ((unsigned)hh << 16) | (unsigned)ll);
            i_ = gatesLB[row * 132 + ul] + xwiB[0];
            f_ = gatesLB[row * 132 + 32 + ul] + xwiB[1];
            g_ = gatesLB[row * 132 + 64 + ul] + xwiB[2];
            o_ = gatesLB[row * 132 + 96 + ul] + xwiB[3];
            c0B = fsig(f_) * c0B + fsig(i_) * ftanh(g_);
            h = fsig(o_) * ftanh(c0B);
            hh = f2bf(h);
            ll = f2bf(h - bf2f(hh));
            astore(h0B[cur] + row * 256 + ug, ((unsigned)hh << 16) | (unsigned)ll);
        }
        asm volatile("s_waitcnt vmcnt(0)" ::: "memory");
        __syncthreads();  // bar2
        if (tid == 0) astore(fl0, (unsigned)(t + 1));
        // ---- prefetch w1l kt 0..7 ----
        uint4 la[8];
#pragma unroll
        for (int kt = 0; kt < 8; ++kt) la[kt] = w1lb[kt * 64];
        // ---- head finish base(t-1) (hides fl0 aging) ----
        if (t > 0) HEADFIN(t - 1);
        // ---- wait + stage h0(t) ----
        WAITF(fl0base, t + 1);
        STAGE(h0A[cur], h0B[cur], 0);
        __syncthreads();  // bar3
        // ---- MV1 partA (Wih1 @ h0(t)) both groups ----
        {
#pragma unroll
            for (int kt = 0; kt < 8; ++kt) {
                int aoff = abase + ((kt * 64 + kgo) ^ aswz);
                bf16x8 ahiA = bcast16(*(const uint4*)(pAhi + aoff));
                bf16x8 aloA = bcast16(*(const uint4*)(pAlo + aoff));
                bf16x8 ahiB = bcast16(*(const uint4*)(pBhi + aoff));
                bf16x8 aloB = bcast16(*(const uint4*)(pBlo + aoff));
                bf16x8 bh = bcast16(w1hR[kt]);
                bf16x8 bl = bcast16(la[kt]);
                acc1A = MFMA(ahiA, bh, acc1A); acc1A = MFMA(aloA, bh, acc1A); acc1A = MFMA(ahiA, bl, acc1A);
                acc1B = MFMA(ahiB, bh, acc1B); acc1B = MFMA(aloB, bh, acc1B); acc1B = MFMA(ahiB, bl, acc1B);
            }
#pragma unroll
            for (int r = 0; r < 4; ++r) {
                gatesLA[(kg * 4 + r) * 132 + gcol] = acc1A[r];
                gatesLB[(kg * 4 + r) * 132 + gcol] = acc1B[r];
            }
        }
        __syncthreads();  // bar4
        // ---- UPD1 both groups -> publish h1(t) ----
        {
            float i_ = gatesLA[row * 132 + ul] + b1v[0];
            float f_ = gatesLA[row * 132 + 32 + ul] + b1v[1];
            float g_ = gatesLA[row * 132 + 64 + ul] + b1v[2];
            float o_ = gatesLA[row * 132 + 96 + ul] + b1v[3];
            c1A = fsig(f_) * c1A + fsig(i_) * ftanh(g_);
            float h = fsig(o_) * ftanh(c1A);
            hsA += h;
            unsigned short hh = f2bf(h);
            unsigned short ll = f2bf(h - bf2f(hh));
            astore(h1A[cur] + row * 256 + ug, ((unsigned)hh << 16) | (unsigned)ll);
            i_ = gatesLB[row * 132 + ul] + b1v[0];
            f_ = gatesLB[row * 132 + 32 + ul] + b1v[1];
            g_ = gatesLB[row * 132 + 64 + ul] + b1v[2];
            o_ = gatesLB[row * 132 + 96 + ul] + b1v[3];
            c1B = fsig(f_) * c1B + fsig(i_) * ftanh(g_);
            h = fsig(o_) * ftanh(c1B);
            hsB += h;
            hh = f2bf(h);
            ll = f2bf(h - bf2f(hh));
            astore(h1B[cur] + row * 256 + ug, ((unsigned)hh << 16) | (unsigned)ll);
        }
        asm volatile("s_waitcnt vmcnt(0)" ::: "memory");
        __syncthreads();  // bar5
        if (tid == 0) astore(fl1, (unsigned)(t + 1));
    }
    // ---- epilogue: base(1919) ----
    WAITF(fl1base, TSTEPS);
    {
        const int prev = (TSTEPS - 1) & 1;
        STAGE(h1A[prev], h1B[prev], 512);
    }
    __syncthreads();
    HEADPART;
    __syncthreads();
    HEADFIN(TSTEPS - 1);
    hsum_out[(gA * 16 + row) * HIDN + ug] = hsA;
    hsum_out[(gB * 16 + row) * HIDN + ug] = hsB;
#undef STAGE
#undef HEADPART
#undef HEADFIN
#undef WAITF
}

__global__ void out_kernel(const float* __restrict__ hsum, const float* __restrict__ oW1,
                           const float* __restrict__ ob1, const float* __restrict__ og,
                           const float* __restrict__ obe, const float* __restrict__ oW2,
                           const float* __restrict__ ob2, const float* __restrict__ base,
                           const int* __restrict__ labels, const float* __restrict__ stress_w,
                           const float* __restrict__ amu_w, const float* __restrict__ amu_b,
                           float* __restrict__ out) {
    int b = blockIdx.x;
    int tid = threadIdx.x;
    int lane = tid & 63, wv = tid >> 6;
    __shared__ float havg[256];
    __shared__ float red[8];
    __shared__ float params[3];
    __shared__ float e_row[TSTEPS];
    havg[tid] = hsum[b * 256 + tid] * (1.f / (float)TSTEPS);
    __syncthreads();
    float d1 = 0.f;
    if (tid < 128) {
        d1 = ob1[tid];
        for (int k = 0; k < 256; ++k) d1 += havg[k] * oW1[tid * 256 + k];
    }
    float s = d1, s2 = d1 * d1;
    for (int o = 1; o < 64; o <<= 1) { s += __shfl_xor(s, o); s2 += __shfl_xor(s2, o); }
    if (lane == 0 && wv < 2) { red[wv] = s; red[2 + wv] = s2; }
    __syncthreads();
    float m = (red[0] + red[1]) * (1.f / 128.f);
    float var = (red[2] + red[3]) * (1.f / 128.f) - m * m;
    float rstd = rsqrtf(var + EPSF);
    float p = 0.f;
    if (tid < 128) p = fleaky((d1 - m) * rstd * og[tid] + obe[tid]);
    float q0 = tid < 128 ? p * oW2[0 * 128 + tid] : 0.f;
    float q1 = tid < 128 ? p * oW2[1 * 128 + tid] : 0.f;
    float q2 = tid < 128 ? p * oW2[2 * 128 + tid] : 0.f;
    for (int o = 1; o < 64; o <<= 1) {
        q0 += __shfl_xor(q0, o); q1 += __shfl_xor(q1, o); q2 += __shfl_xor(q2, o);
    }
    __syncthreads();
    if (lane == 0 && wv < 2) { red[wv] = q0; red[2 + wv] = q1; red[4 + wv] = q2; }
    __syncthreads();
    if (tid == 0) {
        float op0 = red[0] + red[1] + ob2[0];
        float op1 = red[2] + red[3] + ob2[1];
        float op2 = red[4] + red[5] + ob2[2];
        params[0] = 0.23f + 0.04f * ftanh(op0);
        params[1] = 2.0f + 1.5f * ftanh(op1);
        params[2] = 3.14159265358979f * fsig(op2);
    }
    __syncthreads();
    float freq = params[0], amp = params[1], ph = params[2];
    for (int t = tid; t < TSTEPS; t += 256) {
        float x = freq * ((float)TSTEPS * (float)t / (float)(TSTEPS - 1));
        x -= floorf(x);
        float osc = amp * __sinf(6.28318530717958647f * x + ph);
        e_row[t] = 0.6f * base[b * TSTEPS + t] + 0.4f * osc;
    }
    __syncthreads();
    int lab = labels[b];
    float sw = stress_w[0];
    float w0 = amu_w[0], w1 = amu_w[1], w2 = amu_w[2], ab = amu_b[0];
    for (int t = tid; t < TSTEPS; t += 256) {
        float e = e_row[t];
        float r;
        if (lab == 1) r = e;
        else if (lab == 2) r = sw * e;
        else if (lab == 3) {
            float em = t > 0 ? e_row[t - 1] : 0.f;
            float ep = t < TSTEPS - 1 ? e_row[t + 1] : 0.f;
            r = w0 * em + w1 * e + w2 * ep + ab;
        } else r = 0.f;
        out[b * TSTEPS + t] = r;
    }
}

extern "C" void kernel_launch(void* const* d_in, const int* in_sizes, int n_in,
                              void* d_out, int out_size, void* d_ws, size_t ws_size,
                              hipStream_t stream) {
    (void)in_sizes; (void)n_in; (void)out_size; (void)ws_size;
    const float* z      = (const float*)d_in[0];
    const int* labels   = (const int*)d_in[1];
    const float* emb_W  = (const float*)d_in[2];
    const float* np_W   = (const float*)d_in[3];
    const float* np_b   = (const float*)d_in[4];
    const float* np_g   = (const float*)d_in[5];
    const float* np_be  = (const float*)d_in[6];
    const float* Wih0   = (const float*)d_in[7];
    const float* Whh0   = (const float*)d_in[8];
    const float* bih0   = (const float*)d_in[9];
    const float* bhh0   = (const float*)d_in[10];
    const float* Wih1   = (const float*)d_in[11];
    const float* Whh1   = (const float*)d_in[12];
    const float* bih1   = (const float*)d_in[13];
    const float* bhh1   = (const float*)d_in[14];
    const float* oW1    = (const float*)d_in[15];
    const float* ob1    = (const float*)d_in[16];
    const float* og     = (const float*)d_in[17];
    const float* obe    = (const float*)d_in[18];
    const float* oW2    = (const float*)d_in[19];
    const float* ob2    = (const float*)d_in[20];
    const float* sW1    = (const float*)d_in[21];
    const float* sb1    = (const float*)d_in[22];
    const float* sg     = (const float*)d_in[23];
    const float* sbe    = (const float*)d_in[24];
    const float* sW2    = (const float*)d_in[25];
    const float* sb2    = (const float*)d_in[26];
    const float* stressw= (const float*)d_in[27];
    const float* amu_w  = (const float*)d_in[28];
    const float* amu_b  = (const float*)d_in[29];
    float* out = (float*)d_out;

    uint8_t* ws = (uint8_t*)d_ws;
    size_t off = 0;
    unsigned short* whh0h = (unsigned short*)(ws + off); off += (size_t)1024 * 256 * 2;
    unsigned short* whh0l = (unsigned short*)(ws + off); off += (size_t)1024 * 256 * 2;
    unsigned short* w1h   = (unsigned short*)(ws + off); off += (size_t)1024 * 512 * 2;
    unsigned short* w1l   = (unsigned short*)(ws + off); off += (size_t)1024 * 512 * 2;
    unsigned short* sw1k8 = (unsigned short*)(ws + off); off += (size_t)256 * 128 * 2;
    float* Wih0T4 = (float*)(ws + off); off += (size_t)1024 * 512 * 4;
    float* x_const= (float*)(ws + off); off += (size_t)NB * 512 * 4;
    float* xw0    = (float*)(ws + off); off += (size_t)NB * 1024 * 4;
    float* b1sum  = (float*)(ws + off); off += (size_t)1024 * 4;
    float* hsum   = (float*)(ws + off); off += (size_t)NB * 256 * 4;
    float* basef  = (float*)(ws + off); off += (size_t)NB * TSTEPS * 4;
    off = (off + 255) & ~(size_t)255;
    unsigned* hbuf = (unsigned*)(ws + off); off += (size_t)131072 * 4;
    unsigned* flags= (unsigned*)(ws + off); off += (size_t)4096 * 4;

    init_sync<<<512, 256, 0, stream>>>(hbuf, flags);
    pack_bfrag_sliced<<<1024, 256, 0, stream>>>(Whh0, nullptr, 256, 0, whh0h, whh0l);
    pack_bfrag_sliced<<<2048, 256, 0, stream>>>(Wih1, Whh1, 256, 256, w1h, w1l);
    pack_sw1k8<<<128, 256, 0, stream>>>(sW1, sw1k8);
    pack4T<<<2048, 256, 0, stream>>>(Wih0, 1024, 512, Wih0T4);
    prep_b1<<<4, 256, 0, stream>>>(bih1, bhh1, b1sum);

    np_head<<<NB, 256, 0, stream>>>(z, labels, emb_W, np_W, np_b, np_g, np_be, x_const);
    xw0_kernel<<<NB, 1024, 0, stream>>>(x_const, (const float4*)Wih0T4, bih0, bhh0, xw0);
    lstm_coop<<<32, 512, 156160, stream>>>((const uint4*)whh0h, (const uint4*)whh0l,
                                           (const uint4*)w1h, (const uint4*)w1l,
                                           sw1k8, xw0, b1sum, sb1, sg, sbe, sW2, sb2,
                                           hbuf, flags, basef, hsum);
    out_kernel<<<NB, 256, 0, stream>>>(hsum, oW1, ob1, og, obe, oW2, ob2, basef, labels,
                                       stressw, amu_w, amu_b, out);
}

// Round 8
// 27596.094 us; speedup vs baseline: 1.5599x; 1.5599x over previous
//
#include <hip/hip_runtime.h>

#define TSTEPS 1920
#define NB 128
#define HIDN 256
#define LATN 128
#define EPSF 1e-5f

typedef __attribute__((ext_vector_type(8))) short bf16x8;
typedef __attribute__((ext_vector_type(4))) float f32x4;

__device__ __forceinline__ unsigned short f2bf(float x) {
    unsigned u = __builtin_bit_cast(unsigned, x);
    unsigned r = (u + 0x7fffu + ((u >> 16) & 1u)) >> 16;
    return (unsigned short)r;
}
__device__ __forceinline__ float bf2f(unsigned short h) {
    unsigned u = ((unsigned)h) << 16;
    return __builtin_bit_cast(float, u);
}
__device__ __forceinline__ float fsig(float x) {
    float e = __expf(-fabsf(x));
    float s = 1.f / (1.f + e);
    return x >= 0.f ? s : 1.f - s;
}
__device__ __forceinline__ float ftanh(float x) {
    float e = __expf(-2.f * fabsf(x));
    float r = (1.f - e) / (1.f + e);
    return x >= 0.f ? r : -r;
}
__device__ __forceinline__ float fleaky(float x) { return x > 0.f ? x : 0.2f * x; }
__device__ __forceinline__ bf16x8 bcast16(uint4 v) { return __builtin_bit_cast(bf16x8, v); }

__device__ __forceinline__ unsigned aload(const unsigned* p) {
    return __hip_atomic_load(p, __ATOMIC_RELAXED, __HIP_MEMORY_SCOPE_AGENT);
}
__device__ __forceinline__ unsigned long long aload64(const unsigned long long* p) {
    return __hip_atomic_load(p, __ATOMIC_RELAXED, __HIP_MEMORY_SCOPE_AGENT);
}
__device__ __forceinline__ void astore(unsigned* p, unsigned v) {
    __hip_atomic_store(p, v, __ATOMIC_RELAXED, __HIP_MEMORY_SCOPE_AGENT);
}

#define MFMA(a, b, c) __builtin_amdgcn_mfma_f32_16x16x32_bf16((a), (b), (c), 0, 0, 0)

#define FLG(g, s) ((g) * 8 + (s)) * 32
#define HPLANE(g, layer, buf) (((g) * 2 + (layer)) * 2 + (buf)) * 4096

__global__ void init_sync(unsigned* hbuf, unsigned* flags) {
    int i = blockIdx.x * 256 + threadIdx.x;
    if (i < 131072) hbuf[i] = 0u;
    if (i < 4096) flags[i] = 0u;
}

// ---- pack W [1024][KA+KB] -> sliced MFMA B-frag order, hi/lo bf16 ----
__global__ void pack_bfrag_sliced(const float* __restrict__ A, const float* __restrict__ Bsrc,
                                  int KA, int KB,
                                  unsigned short* __restrict__ hi, unsigned short* __restrict__ lo) {
    int e = blockIdx.x * 256 + threadIdx.x;
    int K = KA + KB;
    int KT = K >> 5;
    if (e >= 1024 * K) return;
    int j = e & 7;
    int l = (e >> 3) & 63;
    int r = e >> 9;
    int kt = r % KT;
    int r2 = r / KT;
    int v = r2 & 7;
    int w = r2 >> 3;
    int n = (v >> 1) * 256 + 32 * w + 16 * (v & 1) + (l & 15);
    int k = kt * 32 + (l >> 4) * 8 + j;
    float val = (k < KA) ? A[n * KA + k] : Bsrc[n * KB + (k - KA)];
    unsigned short h = f2bf(val);
    hi[e] = h;
    lo[e] = f2bf(val - bf2f(h));
}

// ---- pack sW1 [128][256] -> B-frag order per (wave, kt): bf16-hi ----
__global__ void pack_sw1frag(const float* __restrict__ sW1, unsigned short* __restrict__ out) {
    int e = blockIdx.x * 256 + threadIdx.x;
    if (e >= 32768) return;
    int j3 = e & 7;
    int l = (e >> 3) & 63;
    int r = e >> 9;           // w*8 + kt
    int kt = r & 7, w = r >> 3;
    int n = w * 16 + (l & 15);
    int k = kt * 32 + (l >> 4) * 8 + j3;
    out[e] = f2bf(sW1[n * 256 + k]);
}

__global__ void pack4T(const float* __restrict__ W, int N, int K, float* __restrict__ out) {
    int e = blockIdx.x * 256 + threadIdx.x;
    if (e >= N * K) return;
    int j = e & 3;
    int rest = e >> 2;
    int n = rest % N;
    int k4 = rest / N;
    out[e] = W[n * K + 4 * k4 + j];
}

__global__ void prep_b1(const float* __restrict__ bih1, const float* __restrict__ bhh1,
                        float* __restrict__ b1sum) {
    int i = blockIdx.x * 256 + threadIdx.x;
    if (i < 1024) b1sum[i] = bih1[i] + bhh1[i];
}

__global__ void np_head(const float* __restrict__ z, const int* __restrict__ labels,
                        const float* __restrict__ emb_W, const float* __restrict__ np_W,
                        const float* __restrict__ np_b, const float* __restrict__ np_g,
                        const float* __restrict__ np_be, float* __restrict__ x_const) {
    int b = blockIdx.x;
    int j = threadIdx.x;
    __shared__ float xc[LATN + HIDN];
    __shared__ float red[8];
    int lab = labels[b];
    if (j < LATN) xc[j] = z[b * LATN + j];
    float e = emb_W[lab * HIDN + j];
    xc[LATN + j] = e;
    __syncthreads();
    float d = np_b[j];
    for (int k = 0; k < LATN + HIDN; ++k) d += xc[k] * np_W[j * (LATN + HIDN) + k];
    int lane = j & 63, wv = j >> 6;
    float s = d, s2 = d * d;
    for (int o = 1; o < 64; o <<= 1) { s += __shfl_xor(s, o); s2 += __shfl_xor(s2, o); }
    if (lane == 0) { red[wv] = s; red[4 + wv] = s2; }
    __syncthreads();
    float S = red[0] + red[1] + red[2] + red[3];
    float S2 = red[4] + red[5] + red[6] + red[7];
    float m = S * (1.f / 256.f);
    float var = S2 * (1.f / 256.f) - m * m;
    float h = fleaky((d - m) * rsqrtf(var + EPSF) * np_g[j] + np_be[j]);
    x_const[b * 512 + j] = h;
    x_const[b * 512 + 256 + j] = e;
}

__global__ void __launch_bounds__(1024) xw0_kernel(const float* __restrict__ x_const,
                                                   const float4* __restrict__ Wih0T4,
                                                   const float* __restrict__ bih0,
                                                   const float* __restrict__ bhh0,
                                                   float* __restrict__ xw0) {
    int b = blockIdx.x;
    int g = threadIdx.x;
    __shared__ float xc[512];
    if (g < 512) xc[g] = x_const[b * 512 + g];
    __syncthreads();
    const float4* xc4 = (const float4*)xc;
    float4 acc = {0.f, 0.f, 0.f, 0.f};
#pragma unroll 8
    for (int k4 = 0; k4 < 128; ++k4) {
        float4 w = Wih0T4[k4 * 1024 + g];
        float4 x = xc4[k4];
        acc.x = fmaf(w.x, x.x, acc.x);
        acc.y = fmaf(w.y, x.y, acc.y);
        acc.z = fmaf(w.z, x.z, acc.z);
        acc.w = fmaf(w.w, x.w, acc.w);
    }
    xw0[b * 1024 + g] = bih0[g] + bhh0[g] + ((acc.x + acc.y) + (acc.z + acc.w));
}

// ==== main recurrent kernel: 64 blocks (8 XCD-groups x 8 slices) x 512 thr ====
// Layer-skewed: phase p computes h0(p) and h1(p-1); ONE sync round per phase.
__global__ void __launch_bounds__(512, 2) lstm_coop(
    const uint4* __restrict__ whh0h, const uint4* __restrict__ whh0l,
    const uint4* __restrict__ w1h, const uint4* __restrict__ w1l,
    const unsigned short* __restrict__ sw1f_g, const float* __restrict__ xw0g,
    const float* __restrict__ b1sum, const float* __restrict__ sb1,
    const float* __restrict__ sg, const float* __restrict__ sbe,
    const float* __restrict__ sW2, const float* __restrict__ sb2,
    unsigned* __restrict__ hbuf, unsigned* __restrict__ flags,
    float* __restrict__ base_out, float* __restrict__ hsum_out) {
    extern __shared__ char smem[];
    char* pHhi = smem;                                        // [16][1024B] hi plane
    char* pHlo = smem + 16384;                                // lo plane
    unsigned short* sw1f = (unsigned short*)(smem + 32768);   // 64KB frag-order bf16
    float* gates0 = (float*)(smem + 98304);                   // [16][132]
    float* gates1 = (float*)(smem + 106752);                  // [16][132]
    float* s1b = (float*)(smem + 115200);                     // [16][132]

    const int gidx = blockIdx.x & 7;   // group == XCD (bid%8 round-robin)
    const int W = blockIdx.x >> 3;     // slice 0..7
    const int g16 = gidx * 16;
    const int tid = threadIdx.x;
    const int l = tid & 63;
    const int v = tid >> 6;            // wave 0..7
    const int ln16 = l & 15;
    const int kg = l >> 4;

    // stage sW1 frags -> LDS
    for (int i = tid; i < 16384; i += 512)
        ((unsigned*)sw1f)[i] = ((const unsigned*)sw1f_g)[i];

    // resident weights
    uint4 b0h[8], b0l[8];
#pragma unroll
    for (int kt = 0; kt < 8; ++kt) {
        int idx = ((W * 8 + v) * 8 + kt) * 64 + l;
        b0h[kt] = whh0h[idx];
        b0l[kt] = whh0l[idx];
    }
    uint4 w1hR[16], w1lR[16];
#pragma unroll
    for (int kt = 0; kt < 16; ++kt) {
        int idx = ((W * 8 + v) * 16 + kt) * 64 + l;
        w1hR[kt] = w1h[idx];
        w1lR[kt] = w1l[idx];
    }

    const int row = tid >> 5;          // batch row 0..15
    const int ul = tid & 31;
    const int ug = 32 * W + ul;        // unit 0..255
    float xwi[4], b1v[4];
#pragma unroll
    for (int gt = 0; gt < 4; ++gt) {
        xwi[gt] = xw0g[(g16 + row) * 1024 + gt * 256 + ug];
        b1v[gt] = b1sum[gt * 256 + ug];
    }
    float c0 = 0.f, c1 = 0.f, hs = 0.f;

    // head lane consts: cols 2l, 2l+1
    const float sb1a = sb1[2 * l], sb1b = sb1[2 * l + 1];
    const float sga = sg[2 * l], sgb = sg[2 * l + 1];
    const float sbea = sbe[2 * l], sbeb = sbe[2 * l + 1];
    const float sw2a = sW2[2 * l], sw2b = sW2[2 * l + 1];
    const float sb2v = sb2[0];

    unsigned* h0buf[2] = {hbuf + HPLANE(gidx, 0, 0), hbuf + HPLANE(gidx, 0, 1)};
    unsigned* h1buf[2] = {hbuf + HPLANE(gidx, 1, 0), hbuf + HPLANE(gidx, 1, 1)};
    unsigned* fl = flags + FLG(gidx, W);
    unsigned* flbase = flags + FLG(gidx, 0);

    const int abase = ln16 * 1024;
    const int aswz = (ln16 & 7) << 4;
    const int kgo = kg * 16;
    const int gcol = (v >> 1) * 32 + (v & 1) * 16 + ln16;

#define WAITF(tgtv)                                                              \
    {                                                                            \
        unsigned tgt = (unsigned)(tgtv);                                         \
        while (true) {                                                           \
            unsigned val = (l < 8) ? aload(flbase + l * 32) : tgt;               \
            if (__all((int)(val >= tgt))) break;                                 \
            __builtin_amdgcn_s_sleep(1);                                         \
        }                                                                        \
    }                                                                            \
    asm volatile("" ::: "memory");

#define STAGE2(src0, src1)                                                       \
    {                                                                            \
        const unsigned long long* sA = (const unsigned long long*)(src0);        \
        const unsigned long long* sB = (const unsigned long long*)(src1);        \
        _Pragma("unroll")                                                        \
        for (int it = 0; it < 4; ++it) {                                         \
            int i2 = tid + 512 * it;                                             \
            int r_ = i2 >> 7, u2 = i2 & 127;                                     \
            int swz = (r_ & 7) << 4;                                             \
            int off0 = r_ * 1024 + ((4 * u2) ^ swz);                             \
            unsigned long long vA = aload64(sA + r_ * 128 + u2);                 \
            unsigned a0 = (unsigned)vA, a1 = (unsigned)(vA >> 32);               \
            *(unsigned*)(pHhi + off0) = (a0 >> 16) | (a1 & 0xffff0000u);         \
            *(unsigned*)(pHlo + off0) = (a0 & 0xffffu) | (a1 << 16);             \
            int off1 = r_ * 1024 + ((512 + 4 * u2) ^ swz);                       \
            unsigned long long vB = aload64(sB + r_ * 128 + u2);                 \
            unsigned e0 = (unsigned)vB, e1 = (unsigned)(vB >> 32);               \
            *(unsigned*)(pHhi + off1) = (e0 >> 16) | (e1 & 0xffff0000u);         \
            *(unsigned*)(pHlo + off1) = (e0 & 0xffffu) | (e1 << 16);             \
        }                                                                        \
    }

#define HEADFIN(tout)                                                            \
    if (v < 4) {                                                                 \
        _Pragma("unroll")                                                        \
        for (int r4 = 0; r4 < 4; ++r4) {                                         \
            int hrw = v * 4 + r4;                                                \
            float2 sv = *(const float2*)&s1b[hrw * 132 + 2 * l];                 \
            float sA = sv.x + sb1a, sB = sv.y + sb1b;                            \
            float ssum = sA + sB, ssq = sA * sA + sB * sB;                       \
            _Pragma("unroll")                                                    \
            for (int o = 1; o < 64; o <<= 1) {                                   \
                ssum += __shfl_xor(ssum, o); ssq += __shfl_xor(ssq, o);          \
            }                                                                    \
            float m = ssum * (1.f / 128.f);                                      \
            float var = ssq * (1.f / 128.f) - m * m;                             \
            float rstd = rsqrtf(var + EPSF);                                     \
            float p0 = fleaky((sA - m) * rstd * sga + sbea);                     \
            float p1 = fleaky((sB - m) * rstd * sgb + sbeb);                     \
            float qd = p0 * sw2a + p1 * sw2b;                                    \
            _Pragma("unroll")                                                    \
            for (int o = 1; o < 64; o <<= 1) qd += __shfl_xor(qd, o);            \
            if (l == 0) base_out[(g16 + hrw) * TSTEPS + (tout)] = ftanh(qd + sb2v); \
        }                                                                        \
    }

    __syncthreads();  // sw1f staged

    for (int p = 0; p <= TSTEPS; ++p) {
        // ---- 1. wait: all blocks published phase p-1 (h0(p-1), h1(p-2)) ----
        WAITF(p);
        // ---- 2. stage h0(p-1) -> bytes [0,512), h1(p-2) -> [512,1024) ----
        STAGE2(h0buf[(p - 1) & 1], h1buf[p & 1]);
        __syncthreads();  // planes ready
        // ---- 3. fused MFMA: gates0, gates1, head ----
        {
            f32x4 a0 = {0.f, 0.f, 0.f, 0.f};   // gates0 = Whh0 @ h0(p-1)
            f32x4 a1 = {0.f, 0.f, 0.f, 0.f};   // gates1 = W1 @ [h0(p-1); h1(p-2)]
            f32x4 ah = {0.f, 0.f, 0.f, 0.f};   // head   = sW1 @ h1(p-2)
#pragma unroll
            for (int kt = 0; kt < 8; ++kt) {   // h0 region: serves MV0 + MV1-A
                int aoff = abase + ((kt * 64 + kgo) ^ aswz);
                bf16x8 ahi = bcast16(*(const uint4*)(pHhi + aoff));
                bf16x8 alo = bcast16(*(const uint4*)(pHlo + aoff));
                bf16x8 bh = bcast16(b0h[kt]);
                bf16x8 bl = bcast16(b0l[kt]);
                a0 = MFMA(ahi, bh, a0); a0 = MFMA(alo, bh, a0); a0 = MFMA(ahi, bl, a0);
                bf16x8 ch = bcast16(w1hR[kt]);
                bf16x8 cl = bcast16(w1lR[kt]);
                a1 = MFMA(ahi, ch, a1); a1 = MFMA(alo, ch, a1); a1 = MFMA(ahi, cl, a1);
            }
#pragma unroll
            for (int kt = 8; kt < 16; ++kt) {  // h1 region: serves MV1-B + head
                int aoff = abase + ((kt * 64 + kgo) ^ aswz);
                bf16x8 ahi = bcast16(*(const uint4*)(pHhi + aoff));
                bf16x8 alo = bcast16(*(const uint4*)(pHlo + aoff));
                bf16x8 ch = bcast16(w1hR[kt]);
                bf16x8 cl = bcast16(w1lR[kt]);
                a1 = MFMA(ahi, ch, a1); a1 = MFMA(alo, ch, a1); a1 = MFMA(ahi, cl, a1);
                bf16x8 bsw = bcast16(*(const uint4*)&sw1f[((v * 8 + (kt - 8)) * 64 + l) * 8]);
                ah = MFMA(ahi, bsw, ah); ah = MFMA(alo, bsw, ah);
            }
#pragma unroll
            for (int r = 0; r < 4; ++r) {
                gates0[(kg * 4 + r) * 132 + gcol] = a0[r];
                gates1[(kg * 4 + r) * 132 + gcol] = a1[r];
                s1b[(kg * 4 + r) * 132 + v * 16 + ln16] = ah[r];
            }
        }
        __syncthreads();  // gates + s1 ready
        // ---- 4. UPD0 -> publish h0(p); UPD1 (p>=1) -> publish h1(p-1) ----
        {
            float i_ = gates0[row * 132 + ul] + xwi[0];
            float f_ = gates0[row * 132 + 32 + ul] + xwi[1];
            float g_ = gates0[row * 132 + 64 + ul] + xwi[2];
            float o_ = gates0[row * 132 + 96 + ul] + xwi[3];
            c0 = fsig(f_) * c0 + fsig(i_) * ftanh(g_);
            float h = fsig(o_) * ftanh(c0);
            unsigned short hh = f2bf(h);
            unsigned short ll = f2bf(h - bf2f(hh));
            astore(h0buf[p & 1] + row * 256 + ug, ((unsigned)hh << 16) | (unsigned)ll);
        }
        if (p > 0) {
            float i_ = gates1[row * 132 + ul] + b1v[0];
            float f_ = gates1[row * 132 + 32 + ul] + b1v[1];
            float g_ = gates1[row * 132 + 64 + ul] + b1v[2];
            float o_ = gates1[row * 132 + 96 + ul] + b1v[3];
            c1 = fsig(f_) * c1 + fsig(i_) * ftanh(g_);
            float h = fsig(o_) * ftanh(c1);
            hs += h;
            unsigned short hh = f2bf(h);
            unsigned short ll = f2bf(h - bf2f(hh));
            astore(h1buf[(p - 1) & 1] + row * 256 + ug, ((unsigned)hh << 16) | (unsigned)ll);
        }
        asm volatile("s_waitcnt vmcnt(0)" ::: "memory");
        __syncthreads();  // publishes done block-wide
        if (tid == 0) astore(fl, (unsigned)(p + 1));
        // ---- 5. head finish base(p-2) (ages next wait) ----
        if (p >= 2) HEADFIN(p - 2);
    }
    // ---- epilogue: base(1919) from h1(1919) ----
    WAITF(TSTEPS + 1);
    STAGE2(h0buf[(TSTEPS + 1 - 1) & 1], h1buf[(TSTEPS + 1) & 1]);  // h1(1919) -> [512,1024)
    __syncthreads();
    {
        f32x4 ah = {0.f, 0.f, 0.f, 0.f};
#pragma unroll
        for (int kt = 8; kt < 16; ++kt) {
            int aoff = abase + ((kt * 64 + kgo) ^ aswz);
            bf16x8 ahi = bcast16(*(const uint4*)(pHhi + aoff));
            bf16x8 alo = bcast16(*(const uint4*)(pHlo + aoff));
            bf16x8 bsw = bcast16(*(const uint4*)&sw1f[((v * 8 + (kt - 8)) * 64 + l) * 8]);
            ah = MFMA(ahi, bsw, ah); ah = MFMA(alo, bsw, ah);
        }
#pragma unroll
        for (int r = 0; r < 4; ++r) s1b[(kg * 4 + r) * 132 + v * 16 + ln16] = ah[r];
    }
    __syncthreads();
    HEADFIN(TSTEPS - 1);
    hsum_out[(g16 + row) * HIDN + ug] = hs;
#undef WAITF
#undef STAGE2
#undef HEADFIN
}

__global__ void out_kernel(const float* __restrict__ hsum, const float* __restrict__ oW1,
                           const float* __restrict__ ob1, const float* __restrict__ og,
                           const float* __restrict__ obe, const float* __restrict__ oW2,
                           const float* __restrict__ ob2, const float* __restrict__ base,
                           const int* __restrict__ labels, const float* __restrict__ stress_w,
                           const float* __restrict__ amu_w, const float* __restrict__ amu_b,
                           float* __restrict__ out) {
    int b = blockIdx.x;
    int tid = threadIdx.x;
    int lane = tid & 63, wv = tid >> 6;
    __shared__ float havg[256];
    __shared__ float red[8];
    __shared__ float params[3];
    __shared__ float e_row[TSTEPS];
    havg[tid] = hsum[b * 256 + tid] * (1.f / (float)TSTEPS);
    __syncthreads();
    float d1 = 0.f;
    if (tid < 128) {
        d1 = ob1[tid];
        for (int k = 0; k < 256; ++k) d1 += havg[k] * oW1[tid * 256 + k];
    }
    float s = d1, s2 = d1 * d1;
    for (int o = 1; o < 64; o <<= 1) { s += __shfl_xor(s, o); s2 += __shfl_xor(s2, o); }
    if (lane == 0 && wv < 2) { red[wv] = s; red[2 + wv] = s2; }
    __syncthreads();
    float m = (red[0] + red[1]) * (1.f / 128.f);
    float var = (red[2] + red[3]) * (1.f / 128.f) - m * m;
    float rstd = rsqrtf(var + EPSF);
    float p = 0.f;
    if (tid < 128) p = fleaky((d1 - m) * rstd * og[tid] + obe[tid]);
    float q0 = tid < 128 ? p * oW2[0 * 128 + tid] : 0.f;
    float q1 = tid < 128 ? p * oW2[1 * 128 + tid] : 0.f;
    float q2 = tid < 128 ? p * oW2[2 * 128 + tid] : 0.f;
    for (int o = 1; o < 64; o <<= 1) {
        q0 += __shfl_xor(q0, o); q1 += __shfl_xor(q1, o); q2 += __shfl_xor(q2, o);
    }
    __syncthreads();
    if (lane == 0 && wv < 2) { red[wv] = q0; red[2 + wv] = q1; red[4 + wv] = q2; }
    __syncthreads();
    if (tid == 0) {
        float op0 = red[0] + red[1] + ob2[0];
        float op1 = red[2] + red[3] + ob2[1];
        float op2 = red[4] + red[5] + ob2[2];
        params[0] = 0.23f + 0.04f * ftanh(op0);
        params[1] = 2.0f + 1.5f * ftanh(op1);
        params[2] = 3.14159265358979f * fsig(op2);
    }
    __syncthreads();
    float freq = params[0], amp = params[1], ph = params[2];
    for (int t = tid; t < TSTEPS; t += 256) {
        float x = freq * ((float)TSTEPS * (float)t / (float)(TSTEPS - 1));
        x -= floorf(x);
        float osc = amp * __sinf(6.28318530717958647f * x + ph);
        e_row[t] = 0.6f * base[b * TSTEPS + t] + 0.4f * osc;
    }
    __syncthreads();
    int lab = labels[b];
    float sw = stress_w[0];
    float w0 = amu_w[0], w1 = amu_w[1], w2 = amu_w[2], ab = amu_b[0];
    for (int t = tid; t < TSTEPS; t += 256) {
        float e = e_row[t];
        float r;
        if (lab == 1) r = e;
        else if (lab == 2) r = sw * e;
        else if (lab == 3) {
            float em = t > 0 ? e_row[t - 1] : 0.f;
            float ep = t < TSTEPS - 1 ? e_row[t + 1] : 0.f;
            r = w0 * em + w1 * e + w2 * ep + ab;
        } else r = 0.f;
        out[b * TSTEPS + t] = r;
    }
}

extern "C" void kernel_launch(void* const* d_in, const int* in_sizes, int n_in,
                              void* d_out, int out_size, void* d_ws, size_t ws_size,
                              hipStream_t stream) {
    (void)in_sizes; (void)n_in; (void)out_size; (void)ws_size;
    const float* z      = (const float*)d_in[0];
    const int* labels   = (const int*)d_in[1];
    const float* emb_W  = (const float*)d_in[2];
    const float* np_W   = (const float*)d_in[3];
    const float* np_b   = (const float*)d_in[4];
    const float* np_g   = (const float*)d_in[5];
    const float* np_be  = (const float*)d_in[6];
    const float* Wih0   = (const float*)d_in[7];
    const float* Whh0   = (const float*)d_in[8];
    const float* bih0   = (const float*)d_in[9];
    const float* bhh0   = (const float*)d_in[10];
    const float* Wih1   = (const float*)d_in[11];
    const float* Whh1   = (const float*)d_in[12];
    const float* bih1   = (const float*)d_in[13];
    const float* bhh1   = (const float*)d_in[14];
    const float* oW1    = (const float*)d_in[15];
    const float* ob1    = (const float*)d_in[16];
    const float* og     = (const float*)d_in[17];
    const float* obe    = (const float*)d_in[18];
    const float* oW2    = (const float*)d_in[19];
    const float* ob2    = (const float*)d_in[20];
    const float* sW1    = (const float*)d_in[21];
    const float* sb1    = (const float*)d_in[22];
    const float* sg     = (const float*)d_in[23];
    const float* sbe    = (const float*)d_in[24];
    const float* sW2    = (const float*)d_in[25];
    const float* sb2    = (const float*)d_in[26];
    const float* stressw= (const float*)d_in[27];
    const float* amu_w  = (const float*)d_in[28];
    const float* amu_b  = (const float*)d_in[29];
    float* out = (float*)d_out;

    uint8_t* ws = (uint8_t*)d_ws;
    size_t off = 0;
    unsigned short* whh0h = (unsigned short*)(ws + off); off += (size_t)1024 * 256 * 2;
    unsigned short* whh0l = (unsigned short*)(ws + off); off += (size_t)1024 * 256 * 2;
    unsigned short* w1h   = (unsigned short*)(ws + off); off += (size_t)1024 * 512 * 2;
    unsigned short* w1l   = (unsigned short*)(ws + off); off += (size_t)1024 * 512 * 2;
    unsigned short* sw1fg = (unsigned short*)(ws + off); off += (size_t)32768 * 2;
    float* Wih0T4 = (float*)(ws + off); off += (size_t)1024 * 512 * 4;
    float* x_const= (float*)(ws + off); off += (size_t)NB * 512 * 4;
    float* xw0    = (float*)(ws + off); off += (size_t)NB * 1024 * 4;
    float* b1sum  = (float*)(ws + off); off += (size_t)1024 * 4;
    float* hsum   = (float*)(ws + off); off += (size_t)NB * 256 * 4;
    float* basef  = (float*)(ws + off); off += (size_t)NB * TSTEPS * 4;
    off = (off + 255) & ~(size_t)255;
    unsigned* hbuf = (unsigned*)(ws + off); off += (size_t)131072 * 4;
    unsigned* flags= (unsigned*)(ws + off); off += (size_t)4096 * 4;

    init_sync<<<512, 256, 0, stream>>>(hbuf, flags);
    pack_bfrag_sliced<<<1024, 256, 0, stream>>>(Whh0, nullptr, 256, 0, whh0h, whh0l);
    pack_bfrag_sliced<<<2048, 256, 0, stream>>>(Wih1, Whh1, 256, 256, w1h, w1l);
    pack_sw1frag<<<128, 256, 0, stream>>>(sW1, sw1fg);
    pack4T<<<2048, 256, 0, stream>>>(Wih0, 1024, 512, Wih0T4);
    prep_b1<<<4, 256, 0, stream>>>(bih1, bhh1, b1sum);

    np_head<<<NB, 256, 0, stream>>>(z, labels, emb_W, np_W, np_b, np_g, np_be, x_const);
    xw0_kernel<<<NB, 1024, 0, stream>>>(x_const, (const float4*)Wih0T4, bih0, bhh0, xw0);
    lstm_coop<<<64, 512, 123648, stream>>>((const uint4*)whh0h, (const uint4*)whh0l,
                                           (const uint4*)w1h, (const uint4*)w1l,
                                           sw1fg, xw0, b1sum, sb1, sg, sbe, sW2, sb2,
                                           hbuf, flags, basef, hsum);
    out_kernel<<<NB, 256, 0, stream>>>(hsum, oW1, ob1, og, obe, oW2, ob2, basef, labels,
                                       stressw, amu_w, amu_b, out);
}